// Round 1
// baseline (238.136 us; speedup 1.0000x reference)
//
#include <hip/hip_runtime.h>
#include <hip/hip_bf16.h>

#define N_NODES 16384
#define N_EDGES 262144
#define MUL 32

__device__ __forceinline__ float silu_f(float x) {
    return x / (1.0f + __expf(-x));
}

// ---------------- K0: zero the histogram + cursor ----------------
__global__ void k_zero(int* __restrict__ counts, int* __restrict__ cursor) {
    int i = blockIdx.x * blockDim.x + threadIdx.x;
    if (i < N_NODES) { counts[i] = 0; cursor[i] = 0; }
}

// ---------------- K1: per-node up projection ----------------
// up[node][0..31]   = s1[k]       = sum_m s[m] * W_up_s[m][k] / sqrt(32)
// up[node][32+3k+i] = v1[k][i]    = sum_m v[m][i] * W_up_v[m][k] / sqrt(32)
__global__ void k_up(const float* __restrict__ nf,
                     const float* __restrict__ Wus,
                     const float* __restrict__ Wuv,
                     float* __restrict__ up) {
    __shared__ float sh[2][128];
    int node0 = blockIdx.x * 2;
    int t = threadIdx.x;                       // 0..255
    sh[t >> 7][t & 127] = nf[(size_t)node0 * 128 + t];
    __syncthreads();
    int local = t >> 7;
    int c = t & 127;
    const float* row = sh[local];
    float acc = 0.f;
    if (c < 32) {
        #pragma unroll
        for (int m = 0; m < 32; ++m) acc += row[m] * Wus[m * 32 + c];
    } else {
        int idx = c - 32;
        int mm = idx / 3, i = idx - mm * 3;    // target channel, component
        #pragma unroll
        for (int m = 0; m < 32; ++m) acc += row[32 + m * 3 + i] * Wuv[m * 32 + mm];
    }
    up[(size_t)(node0 + local) * 128 + c] = acc * 0.17677669529663687f; // 1/sqrt(32)
}

// ---------------- K2: per-edge radial MLP layer-1 (h) + receiver histogram ----------------
__global__ void k_radial(const float* __restrict__ rad,
                         const float* __restrict__ Wr1,
                         const int* __restrict__ recv,
                         float* __restrict__ hbuf,
                         int* __restrict__ counts) {
    int e = blockIdx.x * blockDim.x + threadIdx.x;
    if (e >= N_EDGES) return;
    const float4* rp = (const float4*)(rad + (size_t)e * 8);
    float4 a = rp[0], b = rp[1];
    float r[8] = {a.x, a.y, a.z, a.w, b.x, b.y, b.z, b.w};
    float h[8];
    #pragma unroll
    for (int j = 0; j < 8; ++j) {
        float acc = 0.f;
        #pragma unroll
        for (int k = 0; k < 8; ++k) acc += r[k] * Wr1[k * 8 + j];
        h[j] = silu_f(acc * 0.35355339059327373f);  // 1/sqrt(8)
    }
    float4* hp = (float4*)(hbuf + (size_t)e * 8);
    hp[0] = make_float4(h[0], h[1], h[2], h[3]);
    hp[1] = make_float4(h[4], h[5], h[6], h[7]);
    atomicAdd(&counts[recv[e]], 1);
}

// ---------------- K3: exclusive scan of counts -> starts ----------------
__global__ void k_scan(const int* __restrict__ counts, int* __restrict__ starts) {
    __shared__ int part[256];
    int t = threadIdx.x;
    int base = t * 64;
    int sum = 0;
    for (int i = 0; i < 64; ++i) sum += counts[base + i];
    part[t] = sum;
    __syncthreads();
    for (int off = 1; off < 256; off <<= 1) {
        int v = (t >= off) ? part[t - off] : 0;
        __syncthreads();
        part[t] += v;
        __syncthreads();
    }
    int run = (t == 0) ? 0 : part[t - 1];
    for (int i = 0; i < 64; ++i) { starts[base + i] = run; run += counts[base + i]; }
    if (t == 255) starts[N_NODES] = run;
}

// ---------------- K4: scatter edge ids into receiver-sorted order ----------------
__global__ void k_scatter(const int* __restrict__ recv,
                          const int* __restrict__ starts,
                          int* __restrict__ cursor,
                          int* __restrict__ edge_idx) {
    int e = blockIdx.x * blockDim.x + threadIdx.x;
    if (e >= N_EDGES) return;
    int r = recv[e];
    int pos = starts[r] + atomicAdd(&cursor[r], 1);
    edge_idx[pos] = e;
}

// ---------------- K5: fused gather + message + down-proj + skip + gate ----------------
// 8 nodes per block, 32 lanes per node (lane = channel m).
__launch_bounds__(256)
__global__ void k_gather(const float* __restrict__ up,
                         const float* __restrict__ nf,
                         const float* __restrict__ esh,
                         const float* __restrict__ hbuf,
                         const float* __restrict__ Wr2,
                         const int* __restrict__ senders,
                         const int* __restrict__ starts,
                         const int* __restrict__ edge_idx,
                         const float* __restrict__ Wdns,
                         const float* __restrict__ Wdnv,
                         const float* __restrict__ Wsks,
                         const float* __restrict__ Wskv,
                         const int* __restrict__ species,
                         float* __restrict__ out) {
    __shared__ float agg[8][256];    // per node: S[64] then V[64][3] (m-major)
    __shared__ float snode[8][32];   // skip s
    __shared__ float vnode[8][96];   // skip v (m-major *3)

    int g = threadIdx.x >> 5;   // node slot 0..7
    int m = threadIdx.x & 31;   // channel
    int node = blockIdx.x * 8 + g;

    // stage node_features for the skip connection (coalesced)
    {
        const float* src = nf + (size_t)blockIdx.x * 8 * 128;
        for (int i = threadIdx.x; i < 1024; i += 256) {
            int nn = i >> 7, c = i & 127;
            if (c < 32) snode[nn][c] = src[i];
            else        vnode[nn][c - 32] = src[i];
        }
    }

    int s0 = starts[node], s1 = starts[node + 1];
    float accS0 = 0.f, accS1 = 0.f;
    float accVv0 = 0.f, accVv1 = 0.f, accVv2 = 0.f;
    float accVt0 = 0.f, accVt1 = 0.f, accVt2 = 0.f;

    for (int t = s0; t < s1; ++t) {
        int e = edge_idx[t];
        int snd = senders[e];
        float4 ey = *(const float4*)(esh + (size_t)e * 4);
        float y0 = ey.y, y1 = ey.z, y2 = ey.w;
        const float4* hp4 = (const float4*)(hbuf + (size_t)e * 8);
        float4 ha = hp4[0], hb = hp4[1];
        float h[8] = {ha.x, ha.y, ha.z, ha.w, hb.x, hb.y, hb.z, hb.w};
        float wss = 0.f, wvs = 0.f, wvt = 0.f, wst = 0.f;
        #pragma unroll
        for (int j = 0; j < 8; ++j) {
            float hj = h[j];
            wss += hj * Wr2[j * 128 + m];
            wvs += hj * Wr2[j * 128 + 32 + m];
            wvt += hj * Wr2[j * 128 + 64 + m];
            wst += hj * Wr2[j * 128 + 96 + m];
        }
        const float s8 = 0.35355339059327373f;  // 1/sqrt(8)
        wss *= s8; wvs *= s8; wvt *= s8; wst *= s8;

        const float* uprow = up + (size_t)snd * 128;
        float ss = uprow[m];
        float v0 = uprow[32 + 3 * m + 0];
        float v1v = uprow[32 + 3 * m + 1];
        float v2 = uprow[32 + 3 * m + 2];
        float dot = v0 * y0 + v1v * y1 + v2 * y2;

        accS0 += ss * wss;
        accS1 += dot * 0.5773502691896258f * wst;   // INV_SQRT3
        accVv0 += v0 * wvs; accVv1 += v1v * wvs; accVv2 += v2 * wvs;
        float tv = ss * wvt;
        accVt0 += tv * y0; accVt1 += tv * y1; accVt2 += tv * y2;
    }

    const float inv_neigh = 0.25f;   // AVG_NEIGH^-0.5
    agg[g][m]          = accS0 * inv_neigh;
    agg[g][32 + m]     = accS1 * inv_neigh;
    agg[g][64 + 3 * m + 0]  = accVv0 * inv_neigh;
    agg[g][64 + 3 * m + 1]  = accVv1 * inv_neigh;
    agg[g][64 + 3 * m + 2]  = accVv2 * inv_neigh;
    agg[g][160 + 3 * m + 0] = accVt0 * inv_neigh;
    agg[g][160 + 3 * m + 1] = accVt1 * inv_neigh;
    agg[g][160 + 3 * m + 2] = accVt2 * inv_neigh;
    __syncthreads();

    // ---- down projection: lane m computes output channel k = m ----
    const float* S = agg[g];
    const float* V = agg[g] + 64;
    int sp = species[node];

    float gsa = 0.f, gsb = 0.f, gv0 = 0.f, gv1 = 0.f, gv2 = 0.f;
    #pragma unroll 4
    for (int mm = 0; mm < 64; ++mm) {
        float Sm = S[mm];
        gsa += Sm * Wdns[mm * 64 + m];
        gsb += Sm * Wdns[mm * 64 + 32 + m];
        float wv = Wdnv[mm * 32 + m];
        gv0 += V[mm * 3 + 0] * wv;
        gv1 += V[mm * 3 + 1] * wv;
        gv2 += V[mm * 3 + 2] * wv;
    }
    const float inv8 = 0.125f;   // (2*MUL)^-0.5
    gsa *= inv8; gsb *= inv8; gv0 *= inv8; gv1 *= inv8; gv2 *= inv8;

    float ska = 0.f, skb = 0.f, skv0 = 0.f, skv1 = 0.f, skv2 = 0.f;
    const float* Ws = Wsks + (size_t)sp * 2048;   // [32][64]
    const float* Wv = Wskv + (size_t)sp * 1024;   // [32][32]
    #pragma unroll 4
    for (int mm = 0; mm < 32; ++mm) {
        float sm = snode[g][mm];
        ska += sm * Ws[mm * 64 + m];
        skb += sm * Ws[mm * 64 + 32 + m];
        float wv = Wv[mm * 32 + m];
        skv0 += vnode[g][mm * 3 + 0] * wv;
        skv1 += vnode[g][mm * 3 + 1] * wv;
        skv2 += vnode[g][mm * 3 + 2] * wv;
    }
    const float isq32 = 0.17677669529663687f;  // 1/sqrt(32)
    float a  = 0.5f * (gsa + ska * isq32);
    float b  = 0.5f * (gsb + skb * isq32);
    float o0 = 0.5f * (gv0 + skv0 * isq32);
    float o1 = 0.5f * (gv1 + skv1 * isq32);
    float o2 = 0.5f * (gv2 + skv2 * isq32);

    float feat = silu_f(a);
    float gate = silu_f(b);
    float* o = out + (size_t)node * 128;
    o[m] = feat;
    o[32 + 3 * m + 0] = o0 * gate;
    o[32 + 3 * m + 1] = o1 * gate;
    o[32 + 3 * m + 2] = o2 * gate;
}

extern "C" void kernel_launch(void* const* d_in, const int* in_sizes, int n_in,
                              void* d_out, int out_size, void* d_ws, size_t ws_size,
                              hipStream_t stream) {
    const float* nf   = (const float*)d_in[0];
    const float* esh  = (const float*)d_in[1];
    const float* rad  = (const float*)d_in[2];
    const float* Wus  = (const float*)d_in[3];
    const float* Wuv  = (const float*)d_in[4];
    const float* Wr1  = (const float*)d_in[5];
    const float* Wr2  = (const float*)d_in[6];
    const float* Wdns = (const float*)d_in[7];
    const float* Wdnv = (const float*)d_in[8];
    const float* Wsks = (const float*)d_in[9];
    const float* Wskv = (const float*)d_in[10];
    const int* senders   = (const int*)d_in[11];
    const int* receivers = (const int*)d_in[12];
    const int* species   = (const int*)d_in[13];
    float* out = (float*)d_out;

    // workspace layout (bytes)
    char* ws = (char*)d_ws;
    float* up    = (float*)(ws);                                // 16384*128 f32 = 8 MB
    float* hbuf  = (float*)(ws + 8388608);                      // 262144*8 f32 = 8 MB
    int* counts  = (int*)(ws + 16777216);                       // 64 KB
    int* cursor  = (int*)(ws + 16842752);                       // 64 KB
    int* starts  = (int*)(ws + 16908288);                       // 64 KB + 4
    int* edge_idx = (int*)(ws + 16973840);                      // 1 MB

    k_zero<<<(N_NODES + 255) / 256, 256, 0, stream>>>(counts, cursor);
    k_up<<<N_NODES / 2, 256, 0, stream>>>(nf, Wus, Wuv, up);
    k_radial<<<N_EDGES / 256, 256, 0, stream>>>(rad, Wr1, receivers, hbuf, counts);
    k_scan<<<1, 256, 0, stream>>>(counts, starts);
    k_scatter<<<N_EDGES / 256, 256, 0, stream>>>(receivers, starts, cursor, edge_idx);
    k_gather<<<N_NODES / 8, 256, 0, stream>>>(up, nf, esh, hbuf, Wr2, senders, starts,
                                              edge_idx, Wdns, Wdnv, Wsks, Wskv, species, out);
}

// Round 2
// 209.962 us; speedup vs baseline: 1.1342x; 1.1342x over previous
//
#include <hip/hip_runtime.h>
#include <hip/hip_bf16.h>
#include <hip/hip_fp16.h>

#define N_NODES 16384
#define N_EDGES 262144
#define MUL 32

__device__ __forceinline__ float silu_f(float x) {
    return x / (1.0f + __expf(-x));
}
__device__ __forceinline__ __half2 i2h2(int v) { return __builtin_bit_cast(__half2, v); }
__device__ __forceinline__ int h22i(__half2 v) { return __builtin_bit_cast(int, v); }

// ---------------- K1: per-node up projection (f16 out, channel-major float4 layout) ----------------
// up_h[node*128 + m*4 + {0,1,2,3}] = {s1[m], v1[m][0], v1[m][1], v1[m][2]} as __half
__global__ void k_up(const float* __restrict__ nf,
                     const float* __restrict__ Wus,
                     const float* __restrict__ Wuv,
                     __half* __restrict__ up_h) {
    __shared__ float sh[2][128];
    int node0 = blockIdx.x * 2;
    int t = threadIdx.x;                       // 0..255
    sh[t >> 7][t & 127] = nf[(size_t)node0 * 128 + t];
    __syncthreads();
    int local = t >> 7;
    int c = t & 127;
    int m = c >> 2, comp = c & 3;
    const float* row = sh[local];
    float acc = 0.f;
    if (comp == 0) {
        #pragma unroll
        for (int k = 0; k < 32; ++k) acc += row[k] * Wus[k * 32 + m];
    } else {
        int i = comp - 1;
        #pragma unroll
        for (int k = 0; k < 32; ++k) acc += row[32 + k * 3 + i] * Wuv[k * 32 + m];
    }
    up_h[(size_t)(node0 + local) * 128 + c] = __float2half(acc * 0.17677669529663687f);
}

// ---------------- K2: per-edge radial MLP layer-1 (h, f16) + receiver histogram ----------------
__global__ void k_radial(const float* __restrict__ rad,
                         const float* __restrict__ Wr1,
                         const int* __restrict__ recv,
                         int4* __restrict__ hbuf,   // 8 halves per edge
                         int* __restrict__ counts) {
    int e = blockIdx.x * blockDim.x + threadIdx.x;
    if (e >= N_EDGES) return;
    const float4* rp = (const float4*)(rad + (size_t)e * 8);
    float4 a = rp[0], b = rp[1];
    float r[8] = {a.x, a.y, a.z, a.w, b.x, b.y, b.z, b.w};
    float h[8];
    #pragma unroll
    for (int j = 0; j < 8; ++j) {
        float acc = 0.f;
        #pragma unroll
        for (int k = 0; k < 8; ++k) acc += r[k] * Wr1[k * 8 + j];
        h[j] = silu_f(acc * 0.35355339059327373f);  // 1/sqrt(8)
    }
    int4 o;
    o.x = h22i(__floats2half2_rn(h[0], h[1]));
    o.y = h22i(__floats2half2_rn(h[2], h[3]));
    o.z = h22i(__floats2half2_rn(h[4], h[5]));
    o.w = h22i(__floats2half2_rn(h[6], h[7]));
    hbuf[e] = o;
    atomicAdd(&counts[recv[e]], 1);
}

// ---------------- K3: exclusive scan of 16384 counts -> starts (1024 threads) ----------------
__global__ void k_scan(const int* __restrict__ counts, int* __restrict__ starts) {
    __shared__ int wtot[16];
    __shared__ int woff[16];
    int t = threadIdx.x;          // 0..1023
    int lane = t & 63, wid = t >> 6;
    const int4* cp = (const int4*)(counts + t * 16);
    int4 c0 = cp[0], c1 = cp[1], c2 = cp[2], c3 = cp[3];
    int cs[16] = {c0.x,c0.y,c0.z,c0.w,c1.x,c1.y,c1.z,c1.w,
                  c2.x,c2.y,c2.z,c2.w,c3.x,c3.y,c3.z,c3.w};
    int mysum = 0;
    #pragma unroll
    for (int i = 0; i < 16; ++i) mysum += cs[i];
    // wave-level inclusive scan
    int incl = mysum;
    #pragma unroll
    for (int off = 1; off < 64; off <<= 1) {
        int y = __shfl_up(incl, off, 64);
        if (lane >= off) incl += y;
    }
    if (lane == 63) wtot[wid] = incl;
    __syncthreads();
    if (t == 0) {
        int run = 0;
        #pragma unroll
        for (int w = 0; w < 16; ++w) { woff[w] = run; run += wtot[w]; }
    }
    __syncthreads();
    int run = woff[wid] + (incl - mysum);
    #pragma unroll
    for (int i = 0; i < 16; ++i) { starts[t * 16 + i] = run; run += cs[i]; }
    if (t == 1023) starts[N_NODES] = run;
}

// ---------------- K4: scatter into receiver-sorted 32-B edge records ----------------
// record (8 ints): [snd][y01 h2][y2_ h2][0] [h01][h23][h45][h67]
__global__ void k_scatter(const int* __restrict__ recv,
                          const int* __restrict__ senders,
                          const float* __restrict__ esh,
                          const int4* __restrict__ hbuf,
                          const int* __restrict__ starts,
                          int* __restrict__ cursor,
                          int4* __restrict__ records) {
    int e = blockIdx.x * blockDim.x + threadIdx.x;
    if (e >= N_EDGES) return;
    int r = recv[e];
    float4 ey = *(const float4*)(esh + (size_t)e * 4);
    int4 hb = hbuf[e];
    int pos = starts[r] + atomicAdd(&cursor[r], 1);
    int4 a;
    a.x = senders[e];
    a.y = h22i(__floats2half2_rn(ey.y, ey.z));
    a.z = h22i(__floats2half2_rn(ey.w, 0.f));
    a.w = 0;
    records[2 * (size_t)pos] = a;
    records[2 * (size_t)pos + 1] = hb;
}

// ---------------- K5: fused gather + message + down-proj + skip + gate ----------------
// One wave (64 lanes) per node: 2 edges in flight (sub = lane>>5), 32 channels.
__launch_bounds__(256)
__global__ void k_gather(const __half* __restrict__ up_h,
                         const float* __restrict__ nf,
                         const int4* __restrict__ records,
                         const float* __restrict__ Wr2,
                         const int* __restrict__ starts,
                         const float* __restrict__ Wdns,
                         const float* __restrict__ Wdnv,
                         const float* __restrict__ Wsks,
                         const float* __restrict__ Wskv,
                         const int* __restrict__ species,
                         float* __restrict__ out) {
    __shared__ float agg[4][256];    // per node: S[64] then V[64][3] (m-major)
    __shared__ float snode[4][32];
    __shared__ float vnode[4][96];

    int tid = threadIdx.x;
    int w = tid >> 6;          // node slot 0..3
    int lane = tid & 63;
    int sub = lane >> 5;       // edge sub-slot
    int m = lane & 31;         // channel
    int node = blockIdx.x * 4 + w;

    // stage node_features for the skip connection (coalesced)
    {
        const float* src = nf + (size_t)blockIdx.x * 4 * 128;
        #pragma unroll
        for (int it = 0; it < 2; ++it) {
            int i = tid + it * 256;
            int nn = i >> 7, c = i & 127;
            if (c < 32) snode[nn][c] = src[i];
            else        vnode[nn][c - 32] = src[i];
        }
    }
    __syncthreads();

    int s0 = starts[node], s1 = starts[node + 1];
    float accS0 = 0.f, accS1 = 0.f;
    float accVv0 = 0.f, accVv1 = 0.f, accVv2 = 0.f;
    float accVt0 = 0.f, accVt1 = 0.f, accVt2 = 0.f;

    for (int t0 = s0; t0 < s1; t0 += 2) {
        int t = t0 + sub;
        if (t < s1) {
            const int4* rp = records + 2 * (size_t)t;
            int4 a = rp[0], b = rp[1];
            int snd = a.x;
            float2 y01 = __half22float2(i2h2(a.y));
            float2 y2p = __half22float2(i2h2(a.z));
            float y0 = y01.x, y1 = y01.y, y2 = y2p.x;
            float2 h01 = __half22float2(i2h2(b.x));
            float2 h23 = __half22float2(i2h2(b.y));
            float2 h45 = __half22float2(i2h2(b.z));
            float2 h67 = __half22float2(i2h2(b.w));
            float h[8] = {h01.x, h01.y, h23.x, h23.y, h45.x, h45.y, h67.x, h67.y};

            float wss = 0.f, wvs = 0.f, wvt = 0.f, wst = 0.f;
            #pragma unroll
            for (int j = 0; j < 8; ++j) {
                float hj = h[j];
                wss += hj * Wr2[j * 128 + m];
                wvs += hj * Wr2[j * 128 + 32 + m];
                wvt += hj * Wr2[j * 128 + 64 + m];
                wst += hj * Wr2[j * 128 + 96 + m];
            }
            const float s8 = 0.35355339059327373f;  // 1/sqrt(8)
            wss *= s8; wvs *= s8; wvt *= s8; wst *= s8;

            const int2* uprow = (const int2*)(up_h + (size_t)snd * 128 + m * 4);
            int2 q = *uprow;
            float2 sv0 = __half22float2(i2h2(q.x));
            float2 v12 = __half22float2(i2h2(q.y));
            float ss = sv0.x, v0 = sv0.y, v1v = v12.x, v2 = v12.y;
            float dot = v0 * y0 + v1v * y1 + v2 * y2;

            accS0 += ss * wss;
            accS1 += dot * 0.5773502691896258f * wst;   // INV_SQRT3
            accVv0 += v0 * wvs; accVv1 += v1v * wvs; accVv2 += v2 * wvs;
            float tv = ss * wvt;
            accVt0 += tv * y0; accVt1 += tv * y1; accVt2 += tv * y2;
        }
    }

    // combine the two edge sub-slots
    accS0 += __shfl_xor(accS0, 32, 64);
    accS1 += __shfl_xor(accS1, 32, 64);
    accVv0 += __shfl_xor(accVv0, 32, 64);
    accVv1 += __shfl_xor(accVv1, 32, 64);
    accVv2 += __shfl_xor(accVv2, 32, 64);
    accVt0 += __shfl_xor(accVt0, 32, 64);
    accVt1 += __shfl_xor(accVt1, 32, 64);
    accVt2 += __shfl_xor(accVt2, 32, 64);

    const float inv_neigh = 0.25f;   // AVG_NEIGH^-0.5
    if (sub == 0) {
        agg[w][m]               = accS0 * inv_neigh;
        agg[w][32 + m]          = accS1 * inv_neigh;
        agg[w][64 + 3 * m + 0]  = accVv0 * inv_neigh;
        agg[w][64 + 3 * m + 1]  = accVv1 * inv_neigh;
        agg[w][64 + 3 * m + 2]  = accVv2 * inv_neigh;
        agg[w][160 + 3 * m + 0] = accVt0 * inv_neigh;
        agg[w][160 + 3 * m + 1] = accVt1 * inv_neigh;
        agg[w][160 + 3 * m + 2] = accVt2 * inv_neigh;
    }
    // same-wave LDS write->read: ordered by lgkmcnt, no barrier needed

    const float* S = agg[w];
    const float* V = agg[w] + 64;
    int sp = species[node];

    // down projection split across the two half-waves (mm ranges), combined via shfl
    float gsa = 0.f, gsb = 0.f, gv0 = 0.f, gv1 = 0.f, gv2 = 0.f;
    {
        int mm0 = sub * 32;
        #pragma unroll 4
        for (int k = 0; k < 32; ++k) {
            int mm = mm0 + k;
            float Sm = S[mm];
            gsa += Sm * Wdns[mm * 64 + m];
            gsb += Sm * Wdns[mm * 64 + 32 + m];
            float wv = Wdnv[mm * 32 + m];
            gv0 += V[mm * 3 + 0] * wv;
            gv1 += V[mm * 3 + 1] * wv;
            gv2 += V[mm * 3 + 2] * wv;
        }
    }
    float ska = 0.f, skb = 0.f, skv0 = 0.f, skv1 = 0.f, skv2 = 0.f;
    {
        const float* Ws = Wsks + (size_t)sp * 2048;   // [32][64]
        const float* Wv = Wskv + (size_t)sp * 1024;   // [32][32]
        int mm0 = sub * 16;
        #pragma unroll 4
        for (int k = 0; k < 16; ++k) {
            int mm = mm0 + k;
            float sm = snode[w][mm];
            ska += sm * Ws[mm * 64 + m];
            skb += sm * Ws[mm * 64 + 32 + m];
            float wv = Wv[mm * 32 + m];
            skv0 += vnode[w][mm * 3 + 0] * wv;
            skv1 += vnode[w][mm * 3 + 1] * wv;
            skv2 += vnode[w][mm * 3 + 2] * wv;
        }
    }
    gsa += __shfl_xor(gsa, 32, 64);
    gsb += __shfl_xor(gsb, 32, 64);
    gv0 += __shfl_xor(gv0, 32, 64);
    gv1 += __shfl_xor(gv1, 32, 64);
    gv2 += __shfl_xor(gv2, 32, 64);
    ska += __shfl_xor(ska, 32, 64);
    skb += __shfl_xor(skb, 32, 64);
    skv0 += __shfl_xor(skv0, 32, 64);
    skv1 += __shfl_xor(skv1, 32, 64);
    skv2 += __shfl_xor(skv2, 32, 64);

    if (sub == 0) {
        const float inv8 = 0.125f;                 // (2*MUL)^-0.5
        const float isq32 = 0.17677669529663687f;  // 1/sqrt(32)
        float a  = 0.5f * (gsa * inv8 + ska * isq32);
        float b  = 0.5f * (gsb * inv8 + skb * isq32);
        float o0 = 0.5f * (gv0 * inv8 + skv0 * isq32);
        float o1 = 0.5f * (gv1 * inv8 + skv1 * isq32);
        float o2 = 0.5f * (gv2 * inv8 + skv2 * isq32);

        float feat = silu_f(a);
        float gate = silu_f(b);
        float* o = out + (size_t)node * 128;
        o[m] = feat;
        o[32 + 3 * m + 0] = o0 * gate;
        o[32 + 3 * m + 1] = o1 * gate;
        o[32 + 3 * m + 2] = o2 * gate;
    }
}

extern "C" void kernel_launch(void* const* d_in, const int* in_sizes, int n_in,
                              void* d_out, int out_size, void* d_ws, size_t ws_size,
                              hipStream_t stream) {
    const float* nf   = (const float*)d_in[0];
    const float* esh  = (const float*)d_in[1];
    const float* rad  = (const float*)d_in[2];
    const float* Wus  = (const float*)d_in[3];
    const float* Wuv  = (const float*)d_in[4];
    const float* Wr1  = (const float*)d_in[5];
    const float* Wr2  = (const float*)d_in[6];
    const float* Wdns = (const float*)d_in[7];
    const float* Wdnv = (const float*)d_in[8];
    const float* Wsks = (const float*)d_in[9];
    const float* Wskv = (const float*)d_in[10];
    const int* senders   = (const int*)d_in[11];
    const int* receivers = (const int*)d_in[12];
    const int* species   = (const int*)d_in[13];
    float* out = (float*)d_out;

    // workspace layout (bytes)
    char* ws = (char*)d_ws;
    __half* up_h   = (__half*)(ws);                 // 16384*128 f16 = 4 MB
    int4* hbuf     = (int4*)(ws + (4u << 20));      // 262144*16 B   = 4 MB
    int4* records  = (int4*)(ws + (8u << 20));      // 262144*32 B   = 8 MB
    int* counts    = (int*)(ws + (16u << 20));      // 64 KB
    int* cursor    = (int*)(ws + (16u << 20) + 65536);
    int* starts    = (int*)(ws + (16u << 20) + 131072);   // 64 KB + 4

    hipMemsetAsync(counts, 0, 131072, stream);      // counts + cursor
    k_up<<<N_NODES / 2, 256, 0, stream>>>(nf, Wus, Wuv, up_h);
    k_radial<<<N_EDGES / 256, 256, 0, stream>>>(rad, Wr1, receivers, hbuf, counts);
    k_scan<<<1, 1024, 0, stream>>>(counts, starts);
    k_scatter<<<N_EDGES / 256, 256, 0, stream>>>(receivers, senders, esh, hbuf,
                                                 starts, cursor, records);
    k_gather<<<N_NODES / 4, 256, 0, stream>>>(up_h, nf, records, Wr2, starts,
                                              Wdns, Wdnv, Wsks, Wskv, species, out);
}

// Round 3
// 189.770 us; speedup vs baseline: 1.2549x; 1.1064x over previous
//
#include <hip/hip_runtime.h>
#include <hip/hip_bf16.h>
#include <hip/hip_fp16.h>

#define N_NODES 16384
#define N_EDGES 262144
#define MUL 32

__device__ __forceinline__ float silu_f(float x) {
    return x / (1.0f + __expf(-x));
}
__device__ __forceinline__ __half2 i2h2(int v) { return __builtin_bit_cast(__half2, v); }
__device__ __forceinline__ int h22i(__half2 v) { return __builtin_bit_cast(int, v); }

// ---------------- K1: per-node up projection (f16 out, channel-major float4 layout)
//                 + fused receiver histogram (32 edges per block) ----------------
// up_h[node*128 + m*4 + {0,1,2,3}] = {s1[m], v1[m][0], v1[m][1], v1[m][2]} as __half
__global__ void k_up(const float* __restrict__ nf,
                     const float* __restrict__ Wus,
                     const float* __restrict__ Wuv,
                     __half* __restrict__ up_h,
                     const int* __restrict__ recv,
                     int* __restrict__ counts) {
    __shared__ float sh[2][128];
    int node0 = blockIdx.x * 2;
    int t = threadIdx.x;                       // 0..255
    // fused histogram: 8192 blocks * 32 edges = 262144
    if (t < 32) {
        int e = blockIdx.x * 32 + t;
        atomicAdd(&counts[recv[e]], 1);
    }
    sh[t >> 7][t & 127] = nf[(size_t)node0 * 128 + t];
    __syncthreads();
    int local = t >> 7;
    int c = t & 127;
    int m = c >> 2, comp = c & 3;
    const float* row = sh[local];
    float acc = 0.f;
    if (comp == 0) {
        #pragma unroll
        for (int k = 0; k < 32; ++k) acc += row[k] * Wus[k * 32 + m];
    } else {
        int i = comp - 1;
        #pragma unroll
        for (int k = 0; k < 32; ++k) acc += row[32 + k * 3 + i] * Wuv[k * 32 + m];
    }
    up_h[(size_t)(node0 + local) * 128 + c] = __float2half(acc * 0.17677669529663687f);
}

// ---------------- K2: exclusive scan of 16384 counts -> starts AND cursor ----------------
__global__ void k_scan(const int* __restrict__ counts,
                       int* __restrict__ starts,
                       int* __restrict__ cursor) {
    __shared__ int wtot[16];
    __shared__ int woff[16];
    int t = threadIdx.x;          // 0..1023
    int lane = t & 63, wid = t >> 6;
    const int4* cp = (const int4*)(counts + t * 16);
    int4 c0 = cp[0], c1 = cp[1], c2 = cp[2], c3 = cp[3];
    int cs[16] = {c0.x,c0.y,c0.z,c0.w,c1.x,c1.y,c1.z,c1.w,
                  c2.x,c2.y,c2.z,c2.w,c3.x,c3.y,c3.z,c3.w};
    int mysum = 0;
    #pragma unroll
    for (int i = 0; i < 16; ++i) mysum += cs[i];
    int incl = mysum;
    #pragma unroll
    for (int off = 1; off < 64; off <<= 1) {
        int y = __shfl_up(incl, off, 64);
        if (lane >= off) incl += y;
    }
    if (lane == 63) wtot[wid] = incl;
    __syncthreads();
    if (t == 0) {
        int run = 0;
        #pragma unroll
        for (int w = 0; w < 16; ++w) { woff[w] = run; run += wtot[w]; }
    }
    __syncthreads();
    int run = woff[wid] + (incl - mysum);
    #pragma unroll
    for (int i = 0; i < 16; ++i) {
        starts[t * 16 + i] = run;
        cursor[t * 16 + i] = run;
        run += cs[i];
    }
    if (t == 1023) starts[N_NODES] = run;
}

// ---------------- K3: fused radial MLP + scatter into receiver-sorted 32-B records ----
// record (8 ints): [snd][y01 h2][y2_ h2][0] [h01][h23][h45][h67]
__global__ void k_edges(const float* __restrict__ rad,
                        const float* __restrict__ Wr1,
                        const int* __restrict__ recv,
                        const int* __restrict__ senders,
                        const float* __restrict__ esh,
                        int* __restrict__ cursor,
                        int4* __restrict__ records) {
    int e = blockIdx.x * blockDim.x + threadIdx.x;
    const float4* rp = (const float4*)(rad + (size_t)e * 8);
    float4 a = rp[0], b = rp[1];
    float r[8] = {a.x, a.y, a.z, a.w, b.x, b.y, b.z, b.w};
    float h[8];
    #pragma unroll
    for (int j = 0; j < 8; ++j) {
        float acc = 0.f;
        #pragma unroll
        for (int k = 0; k < 8; ++k) acc += r[k] * Wr1[k * 8 + j];
        h[j] = silu_f(acc * 0.35355339059327373f);  // 1/sqrt(8)
    }
    float4 ey = *(const float4*)(esh + (size_t)e * 4);
    int snd = senders[e];
    int rc = recv[e];
    int pos = atomicAdd(&cursor[rc], 1);
    int4 meta;
    meta.x = snd;
    meta.y = h22i(__floats2half2_rn(ey.y, ey.z));
    meta.z = h22i(__floats2half2_rn(ey.w, 0.f));
    meta.w = 0;
    int4 hp;
    hp.x = h22i(__floats2half2_rn(h[0], h[1]));
    hp.y = h22i(__floats2half2_rn(h[2], h[3]));
    hp.z = h22i(__floats2half2_rn(h[4], h[5]));
    hp.w = h22i(__floats2half2_rn(h[6], h[7]));
    records[2 * (size_t)pos] = meta;
    records[2 * (size_t)pos + 1] = hp;
}

// ---------------- K4: fused gather + message + down-proj + skip + gate ----------------
// One wave (64 lanes) per node: 4 edges in flight (2 sub-slots x 2-unroll), 32 channels.
__launch_bounds__(256, 4)
__global__ void k_gather(const __half* __restrict__ up_h,
                         const float* __restrict__ nf,
                         const int4* __restrict__ records,
                         const float* __restrict__ Wr2,
                         const int* __restrict__ starts,
                         const float* __restrict__ Wdns,
                         const float* __restrict__ Wdnv,
                         const float* __restrict__ Wsks,
                         const float* __restrict__ Wskv,
                         const int* __restrict__ species,
                         float* __restrict__ out) {
    __shared__ float agg[4][256];    // per node: S[64] then V[64][3] (m-major)
    __shared__ float snode[4][32];
    __shared__ float vnode[4][96];

    int tid = threadIdx.x;
    int w = tid >> 6;          // node slot 0..3
    int lane = tid & 63;
    int sub = lane >> 5;       // edge sub-slot
    int m = lane & 31;         // channel
    int node = blockIdx.x * 4 + w;

    // stage node_features for the skip connection (coalesced)
    {
        const float* src = nf + (size_t)blockIdx.x * 4 * 128;
        #pragma unroll
        for (int it = 0; it < 2; ++it) {
            int i = tid + it * 256;
            int nn = i >> 7, c = i & 127;
            if (c < 32) snode[nn][c] = src[i];
            else        vnode[nn][c - 32] = src[i];
        }
    }
    __syncthreads();

    // hoist Wr2 columns into registers; fold 1/sqrt(8) (and 1/sqrt(3) for wst)
    const float s8 = 0.35355339059327373f;
    const float s8s3 = 0.35355339059327373f * 0.5773502691896258f;
    float wr2a[8], wr2b[8], wr2c[8], wr2d[8];
    #pragma unroll
    for (int j = 0; j < 8; ++j) {
        wr2a[j] = Wr2[j * 128 + m] * s8;
        wr2b[j] = Wr2[j * 128 + 32 + m] * s8;
        wr2c[j] = Wr2[j * 128 + 64 + m] * s8;
        wr2d[j] = Wr2[j * 128 + 96 + m] * s8s3;
    }

    int s0 = starts[node], s1 = starts[node + 1];

    float aS0 = 0.f, aS1 = 0.f, aVv0 = 0.f, aVv1 = 0.f, aVv2 = 0.f,
          aVt0 = 0.f, aVt1 = 0.f, aVt2 = 0.f;
    float bS0 = 0.f, bS1 = 0.f, bVv0 = 0.f, bVv1 = 0.f, bVv2 = 0.f,
          bVt0 = 0.f, bVt1 = 0.f, bVt2 = 0.f;

    for (int t0 = s0; t0 < s1; t0 += 4) {
        int ta = t0 + sub;
        int tb = t0 + 2 + sub;
        bool va = ta < s1, vb = tb < s1;
        int4 ra0, ra1, rb0, rb1;
        if (va) { const int4* p = records + 2 * (size_t)ta; ra0 = p[0]; ra1 = p[1]; }
        if (vb) { const int4* p = records + 2 * (size_t)tb; rb0 = p[0]; rb1 = p[1]; }
        int2 qa, qb;
        if (va) qa = *(const int2*)(up_h + (size_t)ra0.x * 128 + m * 4);
        if (vb) qb = *(const int2*)(up_h + (size_t)rb0.x * 128 + m * 4);

        if (va) {
            float2 h01 = __half22float2(i2h2(ra1.x));
            float2 h23 = __half22float2(i2h2(ra1.y));
            float2 h45 = __half22float2(i2h2(ra1.z));
            float2 h67 = __half22float2(i2h2(ra1.w));
            float h[8] = {h01.x, h01.y, h23.x, h23.y, h45.x, h45.y, h67.x, h67.y};
            float wss = 0.f, wvs = 0.f, wvt = 0.f, wst = 0.f;
            #pragma unroll
            for (int j = 0; j < 8; ++j) {
                wss += h[j] * wr2a[j];
                wvs += h[j] * wr2b[j];
                wvt += h[j] * wr2c[j];
                wst += h[j] * wr2d[j];
            }
            float2 y01 = __half22float2(i2h2(ra0.y));
            float2 y2p = __half22float2(i2h2(ra0.z));
            float y0 = y01.x, y1 = y01.y, y2 = y2p.x;
            float2 sv0 = __half22float2(i2h2(qa.x));
            float2 v12 = __half22float2(i2h2(qa.y));
            float ss = sv0.x, v0 = sv0.y, v1v = v12.x, v2 = v12.y;
            float dot = v0 * y0 + v1v * y1 + v2 * y2;
            aS0 += ss * wss;
            aS1 += dot * wst;
            aVv0 += v0 * wvs; aVv1 += v1v * wvs; aVv2 += v2 * wvs;
            float tv = ss * wvt;
            aVt0 += tv * y0; aVt1 += tv * y1; aVt2 += tv * y2;
        }
        if (vb) {
            float2 h01 = __half22float2(i2h2(rb1.x));
            float2 h23 = __half22float2(i2h2(rb1.y));
            float2 h45 = __half22float2(i2h2(rb1.z));
            float2 h67 = __half22float2(i2h2(rb1.w));
            float h[8] = {h01.x, h01.y, h23.x, h23.y, h45.x, h45.y, h67.x, h67.y};
            float wss = 0.f, wvs = 0.f, wvt = 0.f, wst = 0.f;
            #pragma unroll
            for (int j = 0; j < 8; ++j) {
                wss += h[j] * wr2a[j];
                wvs += h[j] * wr2b[j];
                wvt += h[j] * wr2c[j];
                wst += h[j] * wr2d[j];
            }
            float2 y01 = __half22float2(i2h2(rb0.y));
            float2 y2p = __half22float2(i2h2(rb0.z));
            float y0 = y01.x, y1 = y01.y, y2 = y2p.x;
            float2 sv0 = __half22float2(i2h2(qb.x));
            float2 v12 = __half22float2(i2h2(qb.y));
            float ss = sv0.x, v0 = sv0.y, v1v = v12.x, v2 = v12.y;
            float dot = v0 * y0 + v1v * y1 + v2 * y2;
            bS0 += ss * wss;
            bS1 += dot * wst;
            bVv0 += v0 * wvs; bVv1 += v1v * wvs; bVv2 += v2 * wvs;
            float tv = ss * wvt;
            bVt0 += tv * y0; bVt1 += tv * y1; bVt2 += tv * y2;
        }
    }

    float accS0 = aS0 + bS0, accS1 = aS1 + bS1;
    float accVv0 = aVv0 + bVv0, accVv1 = aVv1 + bVv1, accVv2 = aVv2 + bVv2;
    float accVt0 = aVt0 + bVt0, accVt1 = aVt1 + bVt1, accVt2 = aVt2 + bVt2;

    // combine the two edge sub-slots
    accS0 += __shfl_xor(accS0, 32, 64);
    accS1 += __shfl_xor(accS1, 32, 64);
    accVv0 += __shfl_xor(accVv0, 32, 64);
    accVv1 += __shfl_xor(accVv1, 32, 64);
    accVv2 += __shfl_xor(accVv2, 32, 64);
    accVt0 += __shfl_xor(accVt0, 32, 64);
    accVt1 += __shfl_xor(accVt1, 32, 64);
    accVt2 += __shfl_xor(accVt2, 32, 64);

    const float inv_neigh = 0.25f;   // AVG_NEIGH^-0.5
    if (sub == 0) {
        agg[w][m]               = accS0 * inv_neigh;
        agg[w][32 + m]          = accS1 * inv_neigh;
        agg[w][64 + 3 * m + 0]  = accVv0 * inv_neigh;
        agg[w][64 + 3 * m + 1]  = accVv1 * inv_neigh;
        agg[w][64 + 3 * m + 2]  = accVv2 * inv_neigh;
        agg[w][160 + 3 * m + 0] = accVt0 * inv_neigh;
        agg[w][160 + 3 * m + 1] = accVt1 * inv_neigh;
        agg[w][160 + 3 * m + 2] = accVt2 * inv_neigh;
    }
    // same-wave LDS write->read: ordered per wave, no barrier needed

    const float* S = agg[w];
    const float* V = agg[w] + 64;
    int sp = species[node];

    // down projection split across the two half-waves (mm ranges), combined via shfl
    float gsa = 0.f, gsb = 0.f, gv0 = 0.f, gv1 = 0.f, gv2 = 0.f;
    {
        int mm0 = sub * 32;
        #pragma unroll 4
        for (int k = 0; k < 32; ++k) {
            int mm = mm0 + k;
            float Sm = S[mm];
            gsa += Sm * Wdns[mm * 64 + m];
            gsb += Sm * Wdns[mm * 64 + 32 + m];
            float wv = Wdnv[mm * 32 + m];
            gv0 += V[mm * 3 + 0] * wv;
            gv1 += V[mm * 3 + 1] * wv;
            gv2 += V[mm * 3 + 2] * wv;
        }
    }
    float ska = 0.f, skb = 0.f, skv0 = 0.f, skv1 = 0.f, skv2 = 0.f;
    {
        const float* Ws = Wsks + (size_t)sp * 2048;   // [32][64]
        const float* Wv = Wskv + (size_t)sp * 1024;   // [32][32]
        int mm0 = sub * 16;
        #pragma unroll 4
        for (int k = 0; k < 16; ++k) {
            int mm = mm0 + k;
            float sm = snode[w][mm];
            ska += sm * Ws[mm * 64 + m];
            skb += sm * Ws[mm * 64 + 32 + m];
            float wv = Wv[mm * 32 + m];
            skv0 += vnode[w][mm * 3 + 0] * wv;
            skv1 += vnode[w][mm * 3 + 1] * wv;
            skv2 += vnode[w][mm * 3 + 2] * wv;
        }
    }
    gsa += __shfl_xor(gsa, 32, 64);
    gsb += __shfl_xor(gsb, 32, 64);
    gv0 += __shfl_xor(gv0, 32, 64);
    gv1 += __shfl_xor(gv1, 32, 64);
    gv2 += __shfl_xor(gv2, 32, 64);
    ska += __shfl_xor(ska, 32, 64);
    skb += __shfl_xor(skb, 32, 64);
    skv0 += __shfl_xor(skv0, 32, 64);
    skv1 += __shfl_xor(skv1, 32, 64);
    skv2 += __shfl_xor(skv2, 32, 64);

    if (sub == 0) {
        const float inv8 = 0.125f;                 // (2*MUL)^-0.5
        const float isq32 = 0.17677669529663687f;  // 1/sqrt(32)
        float a  = 0.5f * (gsa * inv8 + ska * isq32);
        float b  = 0.5f * (gsb * inv8 + skb * isq32);
        float o0 = 0.5f * (gv0 * inv8 + skv0 * isq32);
        float o1 = 0.5f * (gv1 * inv8 + skv1 * isq32);
        float o2 = 0.5f * (gv2 * inv8 + skv2 * isq32);

        float feat = silu_f(a);
        float gate = silu_f(b);
        float* o = out + (size_t)node * 128;
        o[m] = feat;
        o[32 + 3 * m + 0] = o0 * gate;
        o[32 + 3 * m + 1] = o1 * gate;
        o[32 + 3 * m + 2] = o2 * gate;
    }
}

extern "C" void kernel_launch(void* const* d_in, const int* in_sizes, int n_in,
                              void* d_out, int out_size, void* d_ws, size_t ws_size,
                              hipStream_t stream) {
    const float* nf   = (const float*)d_in[0];
    const float* esh  = (const float*)d_in[1];
    const float* rad  = (const float*)d_in[2];
    const float* Wus  = (const float*)d_in[3];
    const float* Wuv  = (const float*)d_in[4];
    const float* Wr1  = (const float*)d_in[5];
    const float* Wr2  = (const float*)d_in[6];
    const float* Wdns = (const float*)d_in[7];
    const float* Wdnv = (const float*)d_in[8];
    const float* Wsks = (const float*)d_in[9];
    const float* Wskv = (const float*)d_in[10];
    const int* senders   = (const int*)d_in[11];
    const int* receivers = (const int*)d_in[12];
    const int* species   = (const int*)d_in[13];
    float* out = (float*)d_out;

    // workspace layout (bytes)
    char* ws = (char*)d_ws;
    __half* up_h   = (__half*)(ws);                       // 16384*128 f16 = 4 MB
    int4* records  = (int4*)(ws + (4u << 20));            // 262144*32 B   = 8 MB
    int* counts    = (int*)(ws + (12u << 20));            // 64 KB
    int* cursor    = (int*)(ws + (12u << 20) + 65536);    // 64 KB
    int* starts    = (int*)(ws + (12u << 20) + 131072);   // 64 KB + 4

    hipMemsetAsync(counts, 0, 65536, stream);
    k_up<<<N_NODES / 2, 256, 0, stream>>>(nf, Wus, Wuv, up_h, receivers, counts);
    k_scan<<<1, 1024, 0, stream>>>(counts, starts, cursor);
    k_edges<<<N_EDGES / 256, 256, 0, stream>>>(rad, Wr1, receivers, senders, esh,
                                               cursor, records);
    k_gather<<<N_NODES / 4, 256, 0, stream>>>(up_h, nf, records, Wr2, starts,
                                              Wdns, Wdnv, Wsks, Wskv, species, out);
}